// Round 6
// baseline (45.431 us; speedup 1.0000x reference)
//
#include <hip/hip_runtime.h>

// YOLO decode: (32, 3*85, 64, 64) f32 -> (32, 3*64*64, 85) f32
// Wave-private LDS transpose in output layout; no block barrier.
// Loops restructured to compile-time trip counts (5 + tail-20) so the
// compiler fully unrolls and issues all global loads up front (MLP).

#define NB    32
#define NA    3
#define ATTRS 85
#define HH    64
#define WW    64
#define HWSZ  (HH * WW)        // 4096
#define TPW   16               // positions per wave-tile
#define TILES_PER_BA (HWSZ / TPW)   // 256
#define CHUNKS (ATTRS * (TPW / 4))  // 340 float4 chunks per tile = 5*64 + 20
#define WAVE_LDS (TPW * ATTRS)      // 1360 floats per wave

typedef float f32x4 __attribute__((ext_vector_type(4)));

__device__ __forceinline__ float fast_sigmoid(float x) {
    // v_rcp_f32 instead of the full IEEE divide sequence (~1 ulp, fine here)
    return __builtin_amdgcn_rcpf(1.0f + __expf(-x));
}

__global__ __launch_bounds__(256)
void yolo_decode_kernel(const float* __restrict__ in,
                        const float* __restrict__ anchors,
                        const int* __restrict__ imh,
                        const int* __restrict__ imw,
                        float* __restrict__ out)
{
    __shared__ float lds[4 * WAVE_LDS];   // 21760 B -> 7 blocks/CU

    const int tid  = threadIdx.x;
    const int wid  = tid >> 6;
    const int lane = tid & 63;
    float* __restrict__ wlds = lds + wid * WAVE_LDS;

    const int wtile = blockIdx.x * 4 + wid;      // 0 .. 24575
    const int tile  = wtile & (TILES_PER_BA - 1);
    const int ba    = wtile >> 8;                // b*3 + a
    const int b     = ba / NA;
    const int a     = ba - b * NA;
    const int pos0  = tile * TPW;

    const float stride_w = (float)(*imw) / (float)WW;
    const float stride_h = (float)(*imh) / (float)HH;
    const float aw = anchors[a * 2 + 0];
    const float ah = anchors[a * 2 + 1];

    // tile never crosses a grid row (pos0 % 64 in {0,16,32,48})
    const float gy  = (float)(pos0 >> 6);
    const int   gx0 = pos0 & (WW - 1);

    const float* __restrict__ src =
        in + (size_t)(b * (NA * ATTRS) + a * ATTRS) * HWSZ + pos0;

    // ---- load phase: 6 loads issued up front (full unroll + exec-masked tail)
    f32x4 v[6];
#pragma unroll
    for (int k = 0; k < 5; ++k) {
        const int i = k * 64 + lane;
        v[k] = *(const f32x4*)(src + (i >> 2) * HWSZ + (i & 3) * 4);
    }
    const bool tail = (lane < CHUNKS - 5 * 64);   // lane < 20
    if (tail) {
        const int i = 5 * 64 + lane;
        v[5] = *(const f32x4*)(src + (i >> 2) * HWSZ + (i & 3) * 4);
    }

    // ---- transform + scatter into output-layout LDS
#pragma unroll
    for (int k = 0; k < 6; ++k) {
        if (k == 5 && !tail) break;
        const int i    = k * 64 + lane;
        const int attr = i >> 2;
        const int p4   = i & 3;
        float x[4] = {v[k].x, v[k].y, v[k].z, v[k].w};
        float r[4];
        if (attr >= 4) {              // conf + classes: sigmoid
#pragma unroll
            for (int j = 0; j < 4; ++j)
                r[j] = fast_sigmoid(x[j]);
        } else if (attr == 0) {       // box x
#pragma unroll
            for (int j = 0; j < 4; ++j)
                r[j] = (fast_sigmoid(x[j]) + (float)(gx0 + p4 * 4 + j)) * stride_w;
        } else if (attr == 1) {       // box y
#pragma unroll
            for (int j = 0; j < 4; ++j)
                r[j] = (fast_sigmoid(x[j]) + gy) * stride_h;
        } else if (attr == 2) {       // box w
#pragma unroll
            for (int j = 0; j < 4; ++j)
                r[j] = __expf(x[j]) * aw;
        } else {                      // attr == 3: box h
#pragma unroll
            for (int j = 0; j < 4; ++j)
                r[j] = __expf(x[j]) * ah;
        }
#pragma unroll
        for (int j = 0; j < 4; ++j)
            wlds[(p4 * 4 + j) * ATTRS + attr] = r[j];
    }

    // ---- intra-wave only: compiler orders ds_write -> ds_read via lgkmcnt.
    // LDS holds the tile in exact output order -> pure vectorized copy out.
    float* __restrict__ dst =
        out + ((size_t)ba * HWSZ + pos0) * ATTRS;
#pragma unroll
    for (int k = 0; k < 5; ++k) {
        const int i = k * 64 + lane;
        *(f32x4*)(dst + i * 4) = *(const f32x4*)(wlds + i * 4);
    }
    if (tail) {
        const int i = 5 * 64 + lane;
        *(f32x4*)(dst + i * 4) = *(const f32x4*)(wlds + i * 4);
    }
}

extern "C" void kernel_launch(void* const* d_in, const int* in_sizes, int n_in,
                              void* d_out, int out_size, void* d_ws, size_t ws_size,
                              hipStream_t stream) {
    const float* in      = (const float*)d_in[0];
    const float* anchors = (const float*)d_in[1];
    const int*   imh     = (const int*)d_in[2];
    const int*   imw     = (const int*)d_in[3];
    float* out = (float*)d_out;

    const int nwaves  = NB * NA * TILES_PER_BA;  // 24576
    const int nblocks = nwaves / 4;              // 6144
    yolo_decode_kernel<<<nblocks, 256, 0, stream>>>(in, anchors, imh, imw, out);
}